// Round 13
// baseline (178.089 us; speedup 1.0000x reference)
//
#include <hip/hip_runtime.h>
#include <hip/hip_fp16.h>

// MultiHeadAttention_64106681860559 — round 13: faithful m201-style 8-phase
// schedule for the three big GEMMs. 8 phases / 2 K-tiles; 16-MFMA quadrant
// clusters; one half-tile staged per phase; vmcnt(6) twice per iter (counted,
// never 0 mid-loop); fixed buffer roles (buf0=even tiles, buf1=odd).
//
// Workspace (~128 MB):
//   xb fp16 [4096][1024] @0 | wqkvT fp16 [3072][1024] @8M | qkv fp16 [4096][3072] @14M
//   S fp16 [4096][4096] @46M | P fp16 [4096][4096] @78M | vwT fp16 [1024][4096] @118M
//   woutT fp16 [1024][1024] @126M | parts fp16 4x[4096][1024] @14M (qkv+S dead)

typedef _Float16 half_t;
typedef _Float16 half8 __attribute__((ext_vector_type(8)));
typedef _Float16 half4 __attribute__((ext_vector_type(4)));
typedef float f32x4 __attribute__((ext_vector_type(4)));

static constexpr int N_TOK = 4096;
static constexpr int LATENT = 1024;
static constexpr int QKVN = 3072;

#define DEVI __device__ __forceinline__

DEVI void gld_lds16(const half_t* g, half_t* l) {
  __builtin_amdgcn_global_load_lds(
      (const __attribute__((address_space(1))) void*)g,
      (__attribute__((address_space(3))) void*)l,
      16, 0, 0);
}

DEVI f32x4 MFMA(half8 a, half8 b, f32x4 c) {
  return __builtin_amdgcn_mfma_f32_16x16x32_f16(a, b, c, 0, 0, 0);
}

// 128B-row swizzle (R6/R8-proven, 0 conflicts): phys 16B slot p of row r holds
// logical slot p ^ (r&7). Stage pre-swizzles the global source; reads XOR.

// Stage one [128][64] fp16 half-tile (1024 chunks, 512 thr x 2 gld_lds).
DEVI void stage_half(const half_t* __restrict__ g, int ld, half_t* dst, int tid) {
#pragma unroll
  for (int i = 0; i < 2; ++i) {
    int c = tid + i * 512;
    int r = c >> 3;
    int s = c & 7;
    gld_lds16(g + (size_t)r * ld + ((s ^ (r & 7)) * 8), dst + c * 8);
  }
}

DEVI void rdA(half8 dst[4][2], const half_t* Ah, int mbase, int fr, int fs) {
#pragma unroll
  for (int mm = 0; mm < 4; ++mm) {
    int rl = (mbase + mm) * 16 + fr;
#pragma unroll
    for (int kh = 0; kh < 2; ++kh)
      dst[mm][kh] = *(const half8*)(Ah + rl * 64 + (((kh * 4 + fs) ^ (rl & 7)) * 8));
  }
}

DEVI void rdB(half8 dst[2][2], const half_t* Bh, int rbase, int fr, int fs) {
#pragma unroll
  for (int nn = 0; nn < 2; ++nn) {
    int rl = rbase + nn * 16 + fr;
#pragma unroll
    for (int kh = 0; kh < 2; ++kh)
      dst[nn][kh] = *(const half8*)(Bh + rl * 64 + (((kh * 4 + fs) ^ (rl & 7)) * 8));
  }
}

DEVI void mmq(f32x4 acc[8][4], half8 af[4][2], half8 bf[2][2], int mbase, int nbase) {
#pragma unroll
  for (int mm = 0; mm < 4; ++mm)
#pragma unroll
    for (int nn = 0; nn < 2; ++nn) {
      f32x4 c = acc[mbase + mm][nbase + nn];
      c = MFMA(af[mm][0], bf[nn][0], c);
      c = MFMA(af[mm][1], bf[nn][1], c);
      acc[mbase + mm][nbase + nn] = c;
    }
}

#define BAR() __builtin_amdgcn_s_barrier()
#define PRIO(x) __builtin_amdgcn_s_setprio(x)
#define VMCNT6() asm volatile("s_waitcnt vmcnt(6)" ::: "memory")
#define VMCNT0() asm volatile("s_waitcnt vmcnt(0)" ::: "memory")

// ---------------------------------------------------------------------------
// 8-phase 256x256 GEMM: C = A[M][K] @ B^T (B stored [N][K]). 512 thr = 8 waves
// (2Mx4N), per-wave 128x64 (acc[8][4]). LDS: 2buf x 2half x [128][64] x (A,B)
// = 128 KB. 8 phases per 2 K-tiles; per phase: {reads | 1 half-tile stage |
// BAR | prio1 | 16 MFMA quadrant | prio0 | [vmcnt] | BAR}.
// MODE 0: +bias, cols<1024 * 0.125, fp16 (qkv) | MODE 1: fp16 (S) |
// MODE 2: fp16 z-sliced partials (split-K final)
// ---------------------------------------------------------------------------
template <int MODE>
__launch_bounds__(512, 2)
__global__ void gemm8(const half_t* __restrict__ A, int lda,
                      const half_t* __restrict__ B, int ldb,
                      void* __restrict__ Cout, int ldc,
                      const float* __restrict__ bias, int K) {
  __shared__ half_t Al[2][2][128 * 64];  // [buf][half] 64 KB
  __shared__ half_t Bl[2][2][128 * 64];  // 64 KB

  const int tid = threadIdx.x;
  const int lane = tid & 63;
  const int wid = tid >> 6;

  // XCD-aware bijective remap (grids are multiples of 8 per z-slice).
  const int nx = gridDim.x;
  const int nwg = nx * gridDim.y;
  const int bid = blockIdx.y * nx + blockIdx.x;
  const int cpx = nwg >> 3;
  const int swz = (bid & 7) * cpx + (bid >> 3);
  const int rowBlk = (swz / nx) * 256;
  const int colBlk = (swz % nx) * 256;

  const int wr = (wid >> 2) * 128;   // A half index = wid>>2
  const int wc = (wid & 3) * 64;
  const int fr = lane & 15;
  const int fs = lane >> 4;
  const int wcl = wc & 127;          // row base within B half
  const int bh = wc >> 7;            // B half this wave reads

  const int kOff = blockIdx.z * K;
  const half_t* AgH0 = A + (size_t)rowBlk * lda + kOff;
  const half_t* AgH1 = A + (size_t)(rowBlk + 128) * lda + kOff;
  const half_t* BgH0 = B + (size_t)colBlk * ldb + kOff;
  const half_t* BgH1 = B + (size_t)(colBlk + 128) * ldb + kOff;

  const half_t* myA0 = Al[0][wid >> 2];
  const half_t* myA1 = Al[1][wid >> 2];
  const half_t* myB0 = Bl[0][bh];
  const half_t* myB1 = Bl[1][bh];

  f32x4 acc[8][4] = {};
  half8 afA[4][2], afB[4][2], bf01[2][2], bf23[2][2];

  const int NT = K >> 6;   // K-tiles (even; =16 for K=1024)
  const int NI = NT >> 1;  // iterations

  // Prologue: tile0 fully + tile1 all but B-h1 (staged at p1 of iter 0).
  stage_half(AgH0, lda, Al[0][0], tid);
  stage_half(AgH1, lda, Al[0][1], tid);
  stage_half(BgH0, ldb, Bl[0][0], tid);
  stage_half(BgH1, ldb, Bl[0][1], tid);
  stage_half(AgH0 + 64, lda, Al[1][0], tid);
  stage_half(AgH1 + 64, lda, Al[1][1], tid);
  stage_half(BgH0 + 64, ldb, Bl[1][0], tid);
  VMCNT6();  // tile0's 8 ops retired; tile1's 6 may fly
  BAR();

  for (int i = 0; i < NI; ++i) {
    const int t2 = 2 * i + 2;                  // -> buf0
    const int t3 = 2 * i + 3;                  // -> buf1
    const bool g2 = (t2 < NT);
    const bool g3 = (t3 < NT);

    // ---- p1: buf0 afA + bf01; stage B1h1 (tile 2i+1)
    rdA(afA, myA0, 0, fr, fs);
    rdB(bf01, myB0, wcl, fr, fs);
    stage_half(BgH1 + (size_t)(2 * i + 1) * 64, ldb, Bl[1][1], tid);
    BAR(); PRIO(1); mmq(acc, afA, bf01, 0, 0); PRIO(0); BAR();

    // ---- p2: afB
    rdA(afB, myA0, 4, fr, fs);
    BAR(); PRIO(1); mmq(acc, afB, bf01, 4, 0); PRIO(0); BAR();

    // ---- p3: bf23; stage A0 both halves (tile t2)
    rdB(bf23, myB0, wcl + 32, fr, fs);
    if (g2) {
      stage_half(AgH0 + (size_t)t2 * 64, lda, Al[0][0], tid);
      stage_half(AgH1 + (size_t)t2 * 64, lda, Al[0][1], tid);
    }
    BAR(); PRIO(1); mmq(acc, afA, bf23, 0, 2); PRIO(0); BAR();

    // ---- p4: stage B0h0 (t2); counted wait covers p5-p8's inputs
    if (g2) stage_half(BgH0 + (size_t)t2 * 64, ldb, Bl[0][0], tid);
    BAR(); PRIO(1); mmq(acc, afB, bf23, 4, 2); PRIO(0);
    if (g2) VMCNT6(); else VMCNT0();
    BAR();

    // ---- p5: buf1 afA + bf01; stage B0h1 (t2)
    rdA(afA, myA1, 0, fr, fs);
    rdB(bf01, myB1, wcl, fr, fs);
    if (g2) stage_half(BgH1 + (size_t)t2 * 64, ldb, Bl[0][1], tid);
    BAR(); PRIO(1); mmq(acc, afA, bf01, 0, 0); PRIO(0); BAR();

    // ---- p6: afB
    rdA(afB, myA1, 4, fr, fs);
    BAR(); PRIO(1); mmq(acc, afB, bf01, 4, 0); PRIO(0); BAR();

    // ---- p7: bf23; stage A1 both halves (t3)
    rdB(bf23, myB1, wcl + 32, fr, fs);
    if (g3) {
      stage_half(AgH0 + (size_t)t3 * 64, lda, Al[1][0], tid);
      stage_half(AgH1 + (size_t)t3 * 64, lda, Al[1][1], tid);
    }
    BAR(); PRIO(1); mmq(acc, afA, bf23, 0, 2); PRIO(0); BAR();

    // ---- p8: stage B1h0 (t3); counted wait covers next iter's p1-p4
    if (g3) stage_half(BgH0 + (size_t)t3 * 64, ldb, Bl[1][0], tid);
    BAR(); PRIO(1); mmq(acc, afB, bf23, 4, 2); PRIO(0);
    if (g3) VMCNT6();
    BAR();
  }

  // Epilogue. C/D mapping: col = lane&15, row = (lane>>4)*4 + j.
  const size_t zoff = (MODE == 2) ? (size_t)blockIdx.z * N_TOK * ldc : 0;
#pragma unroll
  for (int m = 0; m < 8; ++m) {
#pragma unroll
    for (int n = 0; n < 4; ++n) {
#pragma unroll
      for (int j = 0; j < 4; ++j) {
        int row = rowBlk + wr + m * 16 + (lane >> 4) * 4 + j;
        int col = colBlk + wc + n * 16 + fr;
        float v = acc[m][n][j];
        if (MODE == 0) {
          v += bias[col];
          if (col < 1024) v *= 0.125f;  // fold 1/sqrt(DK) into q
          ((half_t*)Cout)[(size_t)row * ldc + col] = (half_t)v;
        } else if (MODE == 1) {
          ((half_t*)Cout)[(size_t)row * ldc + col] = (half_t)v;
        } else {
          ((half_t*)Cout)[zoff + (size_t)row * ldc + col] = (half_t)v;
        }
      }
    }
  }
}

// ---------------------------------------------------------------------------
// 2-phase 128x128 GEMM — small vwT GEMM only.
// ---------------------------------------------------------------------------
template <int ROWS>
DEVI void stage32(const half_t* __restrict__ g, int ld, half_t* lbase, int tid) {
#pragma unroll
  for (int c = tid; c < ROWS * 4; c += 256) {
    int r = c >> 2;
    int k8 = ((c & 3) ^ ((r >> 1) & 3)) * 8;
    gld_lds16(g + (size_t)r * ld + k8, lbase + c * 8);
  }
}

__launch_bounds__(256, 2)
__global__ void gemm2(const half_t* __restrict__ A, int lda,
                      const half_t* __restrict__ B, int ldb,
                      half_t* __restrict__ Cout, int ldc, int K) {
  constexpr int BM = 128, BN = 128, MF = 4, NF = 4;
  __shared__ half_t At[2][BM * 32];
  __shared__ half_t Bt[2][BN * 32];

  const int tid = threadIdx.x;
  const int lane = tid & 63;
  const int wid = tid >> 6;

  const int nx = gridDim.x;
  const int nwg = nx * gridDim.y;
  const int bid = blockIdx.y * nx + blockIdx.x;
  const int cpx = nwg >> 3;
  const int swz = (bid & 7) * cpx + (bid >> 3);
  const int rowBlk = (swz / nx) * BM;
  const int colBlk = (swz % nx) * BN;

  const int wr = (wid >> 1) * (BM / 2);
  const int wc = (wid & 1) * (BN / 2);
  const int fr = lane & 15;
  const int fs = lane >> 4;

  const half_t* Ag = A + (size_t)rowBlk * lda;
  const half_t* Bg = B + (size_t)colBlk * ldb;

  f32x4 acc[MF][NF] = {};
  const int NT = K >> 5;
  stage32<BM>(Ag, lda, At[0], tid);
  stage32<BN>(Bg, ldb, Bt[0], tid);
  __syncthreads();

  int cur = 0;
  for (int t = 0; t < NT; ++t) {
    if (t + 1 < NT) {
      stage32<BM>(Ag + (t + 1) * 32, lda, At[cur ^ 1], tid);
      stage32<BN>(Bg + (t + 1) * 32, ldb, Bt[cur ^ 1], tid);
    }
    const half_t* Ac = At[cur];
    const half_t* Bc = Bt[cur];
    half8 af[MF], bf[NF];
#pragma unroll
    for (int m = 0; m < MF; ++m) {
      int row = wr + m * 16 + fr;
      af[m] = *(const half8*)(Ac + row * 32 + ((fs ^ ((row >> 1) & 3)) * 8));
    }
#pragma unroll
    for (int n = 0; n < NF; ++n) {
      int row = wc + n * 16 + fr;
      bf[n] = *(const half8*)(Bc + row * 32 + ((fs ^ ((row >> 1) & 3)) * 8));
    }
#pragma unroll
    for (int m = 0; m < MF; ++m)
#pragma unroll
      for (int n = 0; n < NF; ++n)
        acc[m][n] = MFMA(af[m], bf[n], acc[m][n]);
    __syncthreads();
    cur ^= 1;
  }

#pragma unroll
  for (int m = 0; m < MF; ++m)
#pragma unroll
    for (int n = 0; n < NF; ++n)
#pragma unroll
      for (int j = 0; j < 4; ++j) {
        int row = rowBlk + wr + m * 16 + (lane >> 4) * 4 + j;
        int col = colBlk + wc + n * 16 + fr;
        Cout[(size_t)row * ldc + col] = (half_t)acc[m][n][j];
      }
}

// ---------------------------------------------------------------------------
// Split-K reduce: out = sum of 4 fp16 partials + bias (f32 out).
// ---------------------------------------------------------------------------
__launch_bounds__(256)
__global__ void reduce_bias4(const half_t* __restrict__ p, const float* __restrict__ bias,
                             float* __restrict__ out) {
  int i = blockIdx.x * 256 + threadIdx.x;  // half8 index
  const size_t stride8 = (size_t)N_TOK * LATENT / 8;
  half8 a = ((const half8*)p)[i];
  half8 b = ((const half8*)p)[i + stride8];
  half8 c = ((const half8*)p)[i + 2 * stride8];
  half8 d = ((const half8*)p)[i + 3 * stride8];
  float4 e0 = ((const float4*)bias)[(i & 127) * 2];
  float4 e1 = ((const float4*)bias)[(i & 127) * 2 + 1];
  float r[8];
#pragma unroll
  for (int j = 0; j < 8; ++j)
    r[j] = (float)a[j] + (float)b[j] + (float)c[j] + (float)d[j];
  float4 o0, o1;
  o0.x = r[0] + e0.x; o0.y = r[1] + e0.y; o0.z = r[2] + e0.z; o0.w = r[3] + e0.w;
  o1.x = r[4] + e1.x; o1.y = r[5] + e1.y; o1.z = r[6] + e1.z; o1.w = r[7] + e1.w;
  ((float4*)out)[i * 2] = o0;
  ((float4*)out)[i * 2 + 1] = o1;
}

// ---------------------------------------------------------------------------
// Row softmax: S fp16 [4096][4096] -> P fp16. One block (256 thr) per row.
// ---------------------------------------------------------------------------
__launch_bounds__(256)
__global__ void softmax_rows(const half_t* __restrict__ S, half_t* __restrict__ P) {
  const int row = blockIdx.x;
  const int t = threadIdx.x;
  const half8* s8 = (const half8*)(S + (size_t)row * N_TOK);

  half8 v[2];
  float lmax = -1e30f;
#pragma unroll
  for (int i = 0; i < 2; ++i) {
    v[i] = s8[t + i * 256];
#pragma unroll
    for (int j = 0; j < 8; ++j) lmax = fmaxf(lmax, (float)v[i][j]);
  }
#pragma unroll
  for (int off = 32; off; off >>= 1) lmax = fmaxf(lmax, __shfl_xor(lmax, off));

  __shared__ float redm[4];
  __shared__ float reds[4];
  if ((t & 63) == 0) redm[t >> 6] = lmax;
  __syncthreads();
  lmax = fmaxf(fmaxf(redm[0], redm[1]), fmaxf(redm[2], redm[3]));

  float e[16];
  float lsum = 0.f;
#pragma unroll
  for (int i = 0; i < 2; ++i)
#pragma unroll
    for (int j = 0; j < 8; ++j) {
      float ev = __expf((float)v[i][j] - lmax);
      e[i * 8 + j] = ev;
      lsum += ev;
    }
#pragma unroll
  for (int off = 32; off; off >>= 1) lsum += __shfl_xor(lsum, off);
  if ((t & 63) == 0) reds[t >> 6] = lsum;
  __syncthreads();
  float inv = 1.f / (reds[0] + reds[1] + reds[2] + reds[3]);

  half8* p8 = (half8*)(P + (size_t)row * N_TOK);
#pragma unroll
  for (int i = 0; i < 2; ++i) {
    half8 h;
#pragma unroll
    for (int j = 0; j < 8; ++j) h[j] = (half_t)(e[i * 8 + j] * inv);
    p8[t + i * 256] = h;
  }
}

// ---------------------------------------------------------------------------
// Transpose [R][C] -> fp16 [C][R].
// ---------------------------------------------------------------------------
template <typename TI>
__global__ void transpose_to_f16(const TI* __restrict__ in, int ldin,
                                 half_t* __restrict__ out, int ldout) {
  __shared__ float tile[32][33];
  const int cb = blockIdx.x * 32;
  const int rb = blockIdx.y * 32;
  const int tx = threadIdx.x;
#pragma unroll
  for (int i = threadIdx.y; i < 32; i += 8)
    tile[i][tx] = (float)in[(size_t)(rb + i) * ldin + cb + tx];
  __syncthreads();
#pragma unroll
  for (int i = threadIdx.y; i < 32; i += 8)
    out[(size_t)(cb + i) * ldout + rb + tx] = (half_t)tile[tx][i];
}

__global__ void cvt_f32_f16(const float* __restrict__ in, half_t* __restrict__ out) {
  int i = blockIdx.x * 256 + threadIdx.x;
  float4 v = ((const float4*)in)[i];
  half4 h;
  h[0] = (half_t)v.x; h[1] = (half_t)v.y; h[2] = (half_t)v.z; h[3] = (half_t)v.w;
  ((half4*)out)[i] = h;
}

extern "C" void kernel_launch(void* const* d_in, const int* in_sizes, int n_in,
                              void* d_out, int out_size, void* d_ws, size_t ws_size,
                              hipStream_t stream) {
  const float* x = (const float*)d_in[0];
  const float* w_qkv = (const float*)d_in[1];
  const float* b_qkv = (const float*)d_in[2];
  const float* w_out = (const float*)d_in[3];
  const float* b_out = (const float*)d_in[4];
  float* out = (float*)d_out;

  char* ws = (char*)d_ws;
  half_t* xb    = (half_t*)(ws);
  half_t* wqkvT = (half_t*)(ws + ((size_t)8 << 20));
  half_t* qkv   = (half_t*)(ws + ((size_t)14 << 20));
  half_t* S     = (half_t*)(ws + ((size_t)46 << 20));
  half_t* P     = (half_t*)(ws + ((size_t)78 << 20));
  half_t* vwT   = (half_t*)(ws + ((size_t)118 << 20));
  half_t* woutT = (half_t*)(ws + ((size_t)126 << 20));
  half_t* parts = (half_t*)(ws + ((size_t)14 << 20));  // qkv+S dead by then

  dim3 tb(32, 8);

  // 1. x -> fp16
  cvt_f32_f16<<<(N_TOK * LATENT) / (256 * 4), 256, 0, stream>>>(x, xb);
  // 2. w_qkv -> wqkvT [3072][1024] fp16
  transpose_to_f16<float><<<dim3(QKVN / 32, LATENT / 32), tb, 0, stream>>>(w_qkv, QKVN, wqkvT, LATENT);
  // 3. w_out -> woutT [1024][1024] fp16
  transpose_to_f16<float><<<dim3(LATENT / 32, LATENT / 32), tb, 0, stream>>>(w_out, LATENT, woutT, LATENT);
  // 4. qkv = x @ w_qkv + b (q scaled 0.125)  (192 blocks @ 256x256, 8-phase)
  gemm8<0><<<dim3(QKVN / 256, N_TOK / 256), 512, 0, stream>>>(
      xb, LATENT, wqkvT, LATENT, qkv, QKVN, b_qkv, LATENT);
  // 5. vwT[j][t] = sum_c woutT[j][c] * v[t][c]  (256 blocks @ 128x128)
  gemm2<<<dim3(N_TOK / 128, LATENT / 128), 256, 0, stream>>>(
      woutT, LATENT, qkv + 2 * LATENT, QKVN, vwT, N_TOK, LATENT);
  // 6. S = q' @ k^T  (256 blocks @ 256x256, 8-phase)
  gemm8<1><<<dim3(N_TOK / 256, N_TOK / 256), 512, 0, stream>>>(
      qkv, QKVN, qkv + LATENT, QKVN, S, N_TOK, nullptr, LATENT);
  // 7. P = softmax rows
  softmax_rows<<<N_TOK, 256, 0, stream>>>(S, P);
  // 8. parts = P @ vwT, split-K=4, fp16 partials  (4 x 64 blocks @ 256x256)
  gemm8<2><<<dim3(LATENT / 256, N_TOK / 256, 4), 512, 0, stream>>>(
      P, N_TOK, vwT, N_TOK, parts, LATENT, nullptr, 1024);
  // 9. out = sum(parts) + b_out
  reduce_bias4<<<(N_TOK * LATENT) / (256 * 8), 256, 0, stream>>>(parts, b_out, out);
}